// Round 3
// baseline (326.337 us; speedup 1.0000x reference)
//
#include <hip/hip_runtime.h>

// InfoCNECauchy: loss = mean_r log(sum_{j!=r} sim[r,j]) - mean_r log(sim[r, r^4096])
// sim = t^2/(d2+t^2), d2 = ||f_r||^2 + ||f_c||^2 - 2<f_r,f_c>, t=0.07
//
// R3: (a) occupancy 2->4 waves/SIMD: 32x32x16 MFMA (2x2 per wave, 16 frag
// VGPRs vs 32) + __launch_bounds__(256,4) to keep VGPR+AGPR <= 128;
// (b) 4 graph nodes -> 2: prep zeros rowsum+counter, gemm's last block does
// the final log-reduction (device-scope counter + threadfence).

#define N2 8192
#define DIM 512
#define NT 64                       /* 8192/128 tiles per dim */
#define NTILES (NT * (NT + 1) / 2)  /* 2080 upper-triangle tiles */
#define T2 0.0049f

typedef float floatx16 __attribute__((ext_vector_type(16)));
typedef __bf16 bf16x8 __attribute__((ext_vector_type(8)));
typedef __bf16 bf16x4 __attribute__((ext_vector_type(4)));

__device__ __forceinline__ void load_to_lds16(const void* g, void* l) {
  auto gp = (const __attribute__((address_space(1))) void*)(reinterpret_cast<uintptr_t>(g));
  auto lp = (__attribute__((address_space(3))) void*)(reinterpret_cast<uintptr_t>(l));
  __builtin_amdgcn_global_load_lds(gp, lp, 16, 0, 0);
}

// ---- prep: fp32 -> bf16 + row norms + zero rowsum/counter ---------------
__global__ __launch_bounds__(256) void prep_kernel(const float* __restrict__ f,
                                                   __bf16* __restrict__ fbf,
                                                   float* __restrict__ sq,
                                                   float* __restrict__ rowsum,
                                                   int* __restrict__ counter) {
  const int t = threadIdx.x;
  if (t < 2) rowsum[blockIdx.x * 2 + t] = 0.f;
  if (blockIdx.x == 0 && t == 2) *counter = 0;
  const int row = blockIdx.x * 2 + (t >> 7);
  const int ci = (t & 127) * 4;
  const float4 v = *(const float4*)(f + (size_t)row * DIM + ci);
  bf16x4 b;
  b[0] = (__bf16)v.x; b[1] = (__bf16)v.y; b[2] = (__bf16)v.z; b[3] = (__bf16)v.w;
  *(bf16x4*)(fbf + (size_t)row * DIM + ci) = b;
  float s = v.x * v.x + v.y * v.y + v.z * v.z + v.w * v.w;
#pragma unroll
  for (int off = 1; off < 64; off <<= 1) s += __shfl_xor(s, off, 64);
  __shared__ float red[4];
  if ((t & 63) == 0) red[t >> 6] = s;
  __syncthreads();
  if ((t & 127) == 0) sq[row] = red[t >> 6] + red[(t >> 6) + 1];
}

// ---- fused GEMM (upper triangle) + Cauchy epilogue + final reduce -------
__global__ __launch_bounds__(256, 4) void gemm_kernel(const __bf16* __restrict__ fbf,
                                                      const float* __restrict__ sq,
                                                      float* __restrict__ rowsum,
                                                      float* __restrict__ spart,
                                                      int* __restrict__ counter,
                                                      float* __restrict__ out) {
  __shared__ __bf16 aT[128 * 32];  // [rowpair][8 x 16B chunks, XOR-swizzled]
  __shared__ __bf16 bT[128 * 32];

  // triangular decode: row `by` owns tiles bx = by..NT-1
  int idx = blockIdx.x;
  int by = 0, s0 = 0;
  while (s0 + (NT - by) <= idx) { s0 += NT - by; ++by; }
  const int bx = by + (idx - s0);
  const int brow = by * 128;
  const int bcol = bx * 128;
  const bool diag = (by == bx);

  const int t = threadIdx.x;
  const int lane = t & 63;
  const int w = t >> 6;
  const int wrow = (w >> 1) * 64;
  const int wcol = (w & 1) * 64;
  const int l31 = lane & 31;
  const int lh = lane >> 5;  // lane half

  floatx16 acc[2][2] = {};  // 2x2 of 32x32, 64 AGPRs

  // staging lane -> (global row, 16B chunk) under XOR swizzle:
  // LDS slot (rp, u') holds global (row = rp*2 + (u>>2), chunk = u&3), u = u'^(rp&7)
  const __bf16 *gA[2], *gB[2];
#pragma unroll
  for (int it = 0; it < 2; ++it) {
    const int slot = it * 256 + t;
    const int rp = slot >> 3;
    const int u = (slot & 7) ^ (rp & 7);
    const int gr = rp * 2 + (u >> 2);
    const int go = (u & 3) * 8;
    gA[it] = fbf + (size_t)(brow + gr) * DIM + go;
    gB[it] = fbf + (size_t)(bcol + gr) * DIM + go;
  }

  // fragment reads (32x32x16): A row = wrow + mr*32 + l31, chunk = ks*2 + lh
  // rp = row>>1, u = (row&1)*4 + chunk, u' = u ^ (rp&7)
  const int rpA = (wrow >> 1) + (l31 >> 1);  // + mr*16
  const int rpB = (wcol >> 1) + (l31 >> 1);  // + mc*16
  const int xr = (lane >> 1) & 7;            // rp&7
  const int ub = (lane & 1) * 4 + lh;        // + ks*2 (bit1 free)

  for (int kt = 0; kt < DIM / 32; ++kt) {
#pragma unroll
    for (int it = 0; it < 2; ++it) {
      load_to_lds16(gA[it], &aT[t * 8 + it * 2048]);
      load_to_lds16(gB[it], &bT[t * 8 + it * 2048]);
      gA[it] += 32;
      gB[it] += 32;
    }
    __syncthreads();
#pragma unroll
    for (int ks = 0; ks < 2; ++ks) {
      const int up = (ub + ks * 2) ^ xr;
      bf16x8 af[2], bfr[2];
#pragma unroll
      for (int mr = 0; mr < 2; ++mr)
        af[mr] = *(const bf16x8*)&aT[(rpA + mr * 16) * 64 + up * 8];
#pragma unroll
      for (int mc = 0; mc < 2; ++mc)
        bfr[mc] = *(const bf16x8*)&bT[(rpB + mc * 16) * 64 + up * 8];
#pragma unroll
      for (int mr = 0; mr < 2; ++mr)
#pragma unroll
        for (int mc = 0; mc < 2; ++mc)
          acc[mr][mc] = __builtin_amdgcn_mfma_f32_32x32x16_bf16(af[mr], bfr[mc],
                                                                acc[mr][mc], 0, 0, 0);
    }
    __syncthreads();
  }

  // Epilogue. 32x32 C/D layout: col = lane&31, row = (reg&3)+8*(reg>>2)+4*lh.
  float sqc[2];
#pragma unroll
  for (int mc = 0; mc < 2; ++mc) sqc[mc] = sq[bcol + wcol + mc * 32 + l31];

  float cs[2] = {0.f, 0.f};

#pragma unroll
  for (int mr = 0; mr < 2; ++mr) {
#pragma unroll
    for (int reg = 0; reg < 16; ++reg) {
      const int r = brow + wrow + mr * 32 + (reg & 3) + 8 * (reg >> 2) + 4 * lh;
      const float sr = sq[r];
      const int pc = r ^ (N2 / 2);
      float rs = 0.f;
#pragma unroll
      for (int mc = 0; mc < 2; ++mc) {
        const int c = bcol + wcol + mc * 32 + l31;
        const float g = acc[mr][mc][reg];
        const float d2 = fmaxf(sr + sqc[mc] - 2.f * g, 0.f);
        const float s = T2 * __builtin_amdgcn_rcpf(d2 + T2);
        if (c != r) rs += s;  // exact diagonal exclusion (diag tiles only)
        cs[mc] += s;          // unused on diag tiles
        if (c == pc) { spart[r] = s; spart[pc] = s; }  // off-diag, single lane
      }
      // reduce across the 32 lanes of this row's half (xor<32 stays in half)
#pragma unroll
      for (int off = 1; off < 32; off <<= 1) rs += __shfl_xor(rs, off, 64);
      if (l31 == 0) atomicAdd(&rowsum[r], rs);
    }
  }

  if (!diag) {
#pragma unroll
    for (int mc = 0; mc < 2; ++mc) {
      const float v = cs[mc] + __shfl_xor(cs[mc], 32, 64);
      if (lh == 0) atomicAdd(&rowsum[bcol + wcol + mc * 32 + l31], v);
    }
  }

  // ---- last block performs the final reduction --------------------------
  __shared__ int is_last;
  __threadfence();  // release: rowsum/spart visible before counter bump
  if (t == 0) is_last = (atomicAdd(counter, 1) == NTILES - 1);
  __syncthreads();
  if (is_last) {
    __threadfence();  // acquire side
    float a = 0.f;
    for (int r = t; r < N2; r += 256) {
      const float rsv = __hip_atomic_load(&rowsum[r], __ATOMIC_RELAXED, __HIP_MEMORY_SCOPE_AGENT);
      const float spv = __hip_atomic_load(&spart[r], __ATOMIC_RELAXED, __HIP_MEMORY_SCOPE_AGENT);
      a += __logf(rsv) - __logf(spv);
    }
#pragma unroll
    for (int off = 1; off < 64; off <<= 1) a += __shfl_xor(a, off, 64);
    __shared__ float red[4];
    if ((t & 63) == 0) red[t >> 6] = a;
    __syncthreads();
    if (t == 0) out[0] = (red[0] + red[1] + red[2] + red[3]) * (1.0f / (float)N2);
  }
}

extern "C" void kernel_launch(void* const* d_in, const int* in_sizes, int n_in,
                              void* d_out, int out_size, void* d_ws, size_t ws_size,
                              hipStream_t stream) {
  const float* features = (const float*)d_in[0];
  float* out = (float*)d_out;

  char* ws = (char*)d_ws;
  __bf16* fbf = (__bf16*)ws;                                     // 8 MB
  float* sq = (float*)(ws + (size_t)N2 * DIM * sizeof(__bf16));  // 32 KB
  float* rowsum = sq + N2;                                       // 32 KB
  float* spart = rowsum + N2;                                    // 32 KB
  int* counter = (int*)(spart + N2);

  prep_kernel<<<N2 / 2, 256, 0, stream>>>(features, fbf, sq, rowsum, counter);
  gemm_kernel<<<NTILES, 256, 0, stream>>>(fbf, sq, rowsum, spart, counter, out);
}

// Round 4
// 281.079 us; speedup vs baseline: 1.1610x; 1.1610x over previous
//
#include <hip/hip_runtime.h>

// InfoCNECauchy: loss = mean_r log(sum_{j!=r} sim[r,j]) - mean_r log(sim[r, r^4096])
// sim = t^2/(d2+t^2), d2 = ||f_r||^2 + ||f_c||^2 - 2<f_r,f_c>, t=0.07
//
// R4: gemm K-loop reverted to the proven R2 structure (16x16x32, 4x4 accs,
// XOR-swizzled LDS, zero bank conflicts, NO __launch_bounds__ min-waves --
// R3 showed the 128-reg cap squeezes arch VGPRs 80->52 and serializes the
// K-loop on spills). Kept from R3: 2 dispatch nodes instead of 4 (prep zeros
// rowsum+counter; gemm's last block does the final log-reduction).

#define N2 8192
#define DIM 512
#define NT 64                       /* 8192/128 tiles per dim */
#define NTILES (NT * (NT + 1) / 2)  /* 2080 upper-triangle tiles */
#define T2 0.0049f

typedef float floatx4 __attribute__((ext_vector_type(4)));
typedef __bf16 bf16x8 __attribute__((ext_vector_type(8)));
typedef __bf16 bf16x4 __attribute__((ext_vector_type(4)));

__device__ __forceinline__ void load_to_lds16(const void* g, void* l) {
  auto gp = (const __attribute__((address_space(1))) void*)(reinterpret_cast<uintptr_t>(g));
  auto lp = (__attribute__((address_space(3))) void*)(reinterpret_cast<uintptr_t>(l));
  __builtin_amdgcn_global_load_lds(gp, lp, 16, 0, 0);
}

// ---- prep: fp32 -> bf16 + row norms + zero rowsum/counter ---------------
__global__ __launch_bounds__(256) void prep_kernel(const float* __restrict__ f,
                                                   __bf16* __restrict__ fbf,
                                                   float* __restrict__ sq,
                                                   float* __restrict__ rowsum,
                                                   int* __restrict__ counter) {
  const int t = threadIdx.x;
  if (t < 2) rowsum[blockIdx.x * 2 + t] = 0.f;
  if (blockIdx.x == 0 && t == 2) *counter = 0;
  const int row = blockIdx.x * 2 + (t >> 7);
  const int ci = (t & 127) * 4;
  const float4 v = *(const float4*)(f + (size_t)row * DIM + ci);
  bf16x4 b;
  b[0] = (__bf16)v.x; b[1] = (__bf16)v.y; b[2] = (__bf16)v.z; b[3] = (__bf16)v.w;
  *(bf16x4*)(fbf + (size_t)row * DIM + ci) = b;
  float s = v.x * v.x + v.y * v.y + v.z * v.z + v.w * v.w;
#pragma unroll
  for (int off = 1; off < 64; off <<= 1) s += __shfl_xor(s, off, 64);
  __shared__ float red[4];
  if ((t & 63) == 0) red[t >> 6] = s;
  __syncthreads();
  if ((t & 127) == 0) sq[row] = red[t >> 6] + red[(t >> 6) + 1];
}

// ---- fused GEMM (upper triangle) + Cauchy epilogue + final reduce -------
__global__ __launch_bounds__(256) void gemm_kernel(const __bf16* __restrict__ fbf,
                                                   const float* __restrict__ sq,
                                                   float* __restrict__ rowsum,
                                                   float* __restrict__ spart,
                                                   int* __restrict__ counter,
                                                   float* __restrict__ out) {
  __shared__ __bf16 aT[128 * 32];  // [rowpair][8 x 16B chunks, XOR-swizzled]
  __shared__ __bf16 bT[128 * 32];

  // triangular decode: row `by` owns tiles bx = by..NT-1
  int idx = blockIdx.x;
  int by = 0, s0 = 0;
  while (s0 + (NT - by) <= idx) { s0 += NT - by; ++by; }
  const int bx = by + (idx - s0);
  const int brow = by * 128;
  const int bcol = bx * 128;
  const bool diag = (by == bx);

  const int t = threadIdx.x;
  const int lane = t & 63;
  const int w = t >> 6;
  const int wrow = (w >> 1) * 64;
  const int wcol = (w & 1) * 64;
  const int q4 = lane >> 4;  // 0..3
  const int lc = lane & 15;  // 0..15

  floatx4 acc[4][4] = {};

  // staging lane -> (global row, global 16B-chunk) under the XOR swizzle:
  // LDS slot (rp, u') holds global (row = rp*2 + (u>>2), chunk = u&3), u = u'^(rp&7)
  int grow[2], gofs[2];
#pragma unroll
  for (int it = 0; it < 2; ++it) {
    const int slot = it * 256 + t;
    const int rp = slot >> 3;
    const int u = (slot & 7) ^ (rp & 7);
    grow[it] = rp * 2 + (u >> 2);
    gofs[it] = (u & 3) * 8;
  }

  // fragment-read swizzle: for (row rr, chunk q4): u = (rr&1)*4+q4,
  // u' = u ^ (rr>>1 & 7); here rr&1 = lc&1 and (rr>>1)&7 = lc>>1.
  const int up = (((lc & 1) * 4) + q4) ^ (lc >> 1);
  const int rhalf = lc >> 1;

  for (int kt = 0; kt < DIM / 32; ++kt) {
    const int k0 = kt * 32;
#pragma unroll
    for (int it = 0; it < 2; ++it) {
      load_to_lds16(fbf + (size_t)(brow + grow[it]) * DIM + k0 + gofs[it],
                    &aT[t * 8 + it * 2048]);
      load_to_lds16(fbf + (size_t)(bcol + grow[it]) * DIM + k0 + gofs[it],
                    &bT[t * 8 + it * 2048]);
    }
    __syncthreads();
    bf16x8 af[4], bfr[4];
#pragma unroll
    for (int mr = 0; mr < 4; ++mr)
      af[mr] = *(const bf16x8*)&aT[((wrow >> 1) + mr * 8 + rhalf) * 64 + up * 8];
#pragma unroll
    for (int mc = 0; mc < 4; ++mc)
      bfr[mc] = *(const bf16x8*)&bT[((wcol >> 1) + mc * 8 + rhalf) * 64 + up * 8];
#pragma unroll
    for (int mr = 0; mr < 4; ++mr)
#pragma unroll
      for (int mc = 0; mc < 4; ++mc)
        acc[mr][mc] =
            __builtin_amdgcn_mfma_f32_16x16x32_bf16(af[mr], bfr[mc], acc[mr][mc], 0, 0, 0);
    __syncthreads();
  }

  // Epilogue. C/D layout: col = lane&15, row = (lane>>4)*4 + reg.
  float sqc[4];
#pragma unroll
  for (int mc = 0; mc < 4; ++mc) sqc[mc] = sq[bcol + wcol + mc * 16 + lc];

  float cs[4] = {0.f, 0.f, 0.f, 0.f};  // column partial sums (off-diag tiles)

#pragma unroll
  for (int mr = 0; mr < 4; ++mr) {
#pragma unroll
    for (int reg = 0; reg < 4; ++reg) {
      const int r = brow + wrow + mr * 16 + q4 * 4 + reg;
      const float sr = sq[r];
      const int pc = r ^ (N2 / 2);
      float rs = 0.f;
#pragma unroll
      for (int mc = 0; mc < 4; ++mc) {
        const int c = bcol + wcol + mc * 16 + lc;
        const float g = acc[mr][mc][reg];
        const float d2 = fmaxf(sr + sqc[mc] - 2.f * g, 0.f);
        const float s = T2 * __builtin_amdgcn_rcpf(d2 + T2);
        if (c != r) rs += s;  // diagonal excluded exactly (diag tiles only)
        cs[mc] += s;          // unused on diag tiles
        if (c == pc) { spart[r] = s; spart[pc] = s; }  // off-diag only, 1 lane
      }
#pragma unroll
      for (int off = 1; off < 16; off <<= 1) rs += __shfl_xor(rs, off, 64);
      if (lc == 0) atomicAdd(&rowsum[r], rs);
    }
  }

  if (!diag) {
    // column sums: reduce the 4 q4 groups (lanes 16 apart), one atomic/col
#pragma unroll
    for (int mc = 0; mc < 4; ++mc) {
      float v = cs[mc];
      v += __shfl_xor(v, 16, 64);
      v += __shfl_xor(v, 32, 64);
      if (lane < 16) atomicAdd(&rowsum[bcol + wcol + mc * 16 + lane], v);
    }
  }

  // ---- last block performs the final reduction --------------------------
  __shared__ int is_last;
  __threadfence();  // release: rowsum/spart visible before counter bump
  if (t == 0) is_last = (atomicAdd(counter, 1) == NTILES - 1);
  __syncthreads();
  if (is_last) {
    __threadfence();  // acquire side
    float a = 0.f;
    for (int r = t; r < N2; r += 256) {
      const float rsv = __hip_atomic_load(&rowsum[r], __ATOMIC_RELAXED, __HIP_MEMORY_SCOPE_AGENT);
      const float spv = __hip_atomic_load(&spart[r], __ATOMIC_RELAXED, __HIP_MEMORY_SCOPE_AGENT);
      a += __logf(rsv) - __logf(spv);
    }
#pragma unroll
    for (int off = 1; off < 64; off <<= 1) a += __shfl_xor(a, off, 64);
    __shared__ float red[4];
    if ((t & 63) == 0) red[t >> 6] = a;
    __syncthreads();
    if (t == 0) out[0] = (red[0] + red[1] + red[2] + red[3]) * (1.0f / (float)N2);
  }
}

extern "C" void kernel_launch(void* const* d_in, const int* in_sizes, int n_in,
                              void* d_out, int out_size, void* d_ws, size_t ws_size,
                              hipStream_t stream) {
  const float* features = (const float*)d_in[0];
  float* out = (float*)d_out;

  char* ws = (char*)d_ws;
  __bf16* fbf = (__bf16*)ws;                                     // 8 MB
  float* sq = (float*)(ws + (size_t)N2 * DIM * sizeof(__bf16));  // 32 KB
  float* rowsum = sq + N2;                                       // 32 KB
  float* spart = rowsum + N2;                                    // 32 KB
  int* counter = (int*)(spart + N2);

  prep_kernel<<<N2 / 2, 256, 0, stream>>>(features, fbf, sq, rowsum, counter);
  gemm_kernel<<<NTILES, 256, 0, stream>>>(fbf, sq, rowsum, spart, counter, out);
}

// Round 5
// 143.658 us; speedup vs baseline: 2.2716x; 1.9566x over previous
//
#include <hip/hip_runtime.h>

// InfoCNECauchy: loss = mean_r log(sum_{j!=r} sim[r,j]) - mean_r log(sim[r, r^4096])
// sim = t^2/(d2+t^2), d2 = ||f_r||^2 + ||f_c||^2 - 2<f_r,f_c>, t=0.07
//
// R5: R2's proven gemm body (16x16x32, 4x4 accs, XOR-swizzled LDS, 0 bank
// conflicts). NO in-kernel fence/tail (R3/R4 proved per-block agent fences
// poison L2 -> 2.6x). New: XCD-aware tile scheduling. blockIdx%8 -> XCD;
// XCD x owns row-bands by in [4x,4x+4) and [60-4x,64-4x) (260 tiles each),
// bx-major, so each XCD's resident blocks fit a ~3MB panel set in its 4MB
// L2 -- converting the 6.3 TB/s L3-fabric stream (the measured bottleneck)
// into L2 hits.

#define N2 8192
#define DIM 512
#define NT 64 /* 8192/128 tiles per dim */
#define NTILES (NT * (NT + 1) / 2)
#define T2 0.0049f

typedef float floatx4 __attribute__((ext_vector_type(4)));
typedef __bf16 bf16x8 __attribute__((ext_vector_type(8)));
typedef __bf16 bf16x4 __attribute__((ext_vector_type(4)));

__device__ __forceinline__ void load_to_lds16(const void* g, void* l) {
  auto gp = (const __attribute__((address_space(1))) void*)(reinterpret_cast<uintptr_t>(g));
  auto lp = (__attribute__((address_space(3))) void*)(reinterpret_cast<uintptr_t>(l));
  __builtin_amdgcn_global_load_lds(gp, lp, 16, 0, 0);
}

// ---- prep: fp32 -> bf16 + row norms + zero rowsum ------------------------
__global__ __launch_bounds__(256) void prep_kernel(const float* __restrict__ f,
                                                   __bf16* __restrict__ fbf,
                                                   float* __restrict__ sq,
                                                   float* __restrict__ rowsum) {
  const int t = threadIdx.x;
  if (t < 2) rowsum[blockIdx.x * 2 + t] = 0.f;
  const int row = blockIdx.x * 2 + (t >> 7);
  const int ci = (t & 127) * 4;
  const float4 v = *(const float4*)(f + (size_t)row * DIM + ci);
  bf16x4 b;
  b[0] = (__bf16)v.x; b[1] = (__bf16)v.y; b[2] = (__bf16)v.z; b[3] = (__bf16)v.w;
  *(bf16x4*)(fbf + (size_t)row * DIM + ci) = b;
  float s = v.x * v.x + v.y * v.y + v.z * v.z + v.w * v.w;
#pragma unroll
  for (int off = 1; off < 64; off <<= 1) s += __shfl_xor(s, off, 64);
  __shared__ float red[4];
  if ((t & 63) == 0) red[t >> 6] = s;
  __syncthreads();
  if ((t & 127) == 0) sq[row] = red[t >> 6] + red[(t >> 6) + 1];
}

// ---- fused GEMM (upper triangle, XCD-banded order) + Cauchy epilogue -----
__global__ __launch_bounds__(256) void gemm_kernel(const __bf16* __restrict__ fbf,
                                                   const float* __restrict__ sq,
                                                   float* __restrict__ rowsum,
                                                   float* __restrict__ spart) {
  __shared__ __bf16 aT[128 * 32];  // [rowpair][8 x 16B chunks, XOR-swizzled]
  __shared__ __bf16 bT[128 * 32];

  // XCD-banded tile decode: x = blockIdx%8 (XCD), k = blockIdx/8 (0..259).
  // XCD x enumerates band x (by0=4x, 250-16x tiles) then band 15-x
  // (by0=60-4x, 10+16x tiles), each bx-major with by in [by0, min(by0+4,bx+1)).
  {
    const int x = blockIdx.x & 7;
    int kk = blockIdx.x >> 3;
    int band = x;
    const int n1 = 250 - 16 * x;
    if (kk >= n1) { kk -= n1; band = 15 - x; }
    const int by0 = band * 4;
    int bxx = by0;
    int cnt;
    while (kk >= (cnt = min(4, bxx - by0 + 1))) { kk -= cnt; ++bxx; }
    // store into the shared names used below
    __shared__ int s_by, s_bx;
    if (threadIdx.x == 0) { s_by = by0 + kk; s_bx = bxx; }
    __syncthreads();
    (void)s_by;  // (decode is uniform; shared broadcast avoids per-lane loop divergence)
  }
  // re-derive uniformly per thread (scalar-unit friendly, no shared needed)
  int by, bx;
  {
    const int x = blockIdx.x & 7;
    int kk = blockIdx.x >> 3;
    int band = x;
    const int n1 = 250 - 16 * x;
    if (kk >= n1) { kk -= n1; band = 15 - x; }
    const int by0 = band * 4;
    int bxx = by0;
    int cnt;
    while (kk >= (cnt = min(4, bxx - by0 + 1))) { kk -= cnt; ++bxx; }
    by = by0 + kk;
    bx = bxx;
  }
  const int brow = by * 128;
  const int bcol = bx * 128;
  const bool diag = (by == bx);

  const int t = threadIdx.x;
  const int lane = t & 63;
  const int w = t >> 6;
  const int wrow = (w >> 1) * 64;
  const int wcol = (w & 1) * 64;
  const int q4 = lane >> 4;  // 0..3
  const int lc = lane & 15;  // 0..15

  floatx4 acc[4][4] = {};

  // staging lane -> (global row, 16B chunk) under XOR swizzle:
  // LDS slot (rp, u') holds global (row = rp*2 + (u>>2), chunk = u&3), u = u'^(rp&7)
  int grow[2], gofs[2];
#pragma unroll
  for (int it = 0; it < 2; ++it) {
    const int slot = it * 256 + t;
    const int rp = slot >> 3;
    const int u = (slot & 7) ^ (rp & 7);
    grow[it] = rp * 2 + (u >> 2);
    gofs[it] = (u & 3) * 8;
  }

  // fragment-read swizzle: u = (rr&1)*4+q4, u' = u ^ ((rr>>1)&7); rr = lc here.
  const int up = (((lc & 1) * 4) + q4) ^ (lc >> 1);
  const int rhalf = lc >> 1;

  for (int kt = 0; kt < DIM / 32; ++kt) {
    const int k0 = kt * 32;
#pragma unroll
    for (int it = 0; it < 2; ++it) {
      load_to_lds16(fbf + (size_t)(brow + grow[it]) * DIM + k0 + gofs[it],
                    &aT[t * 8 + it * 2048]);
      load_to_lds16(fbf + (size_t)(bcol + grow[it]) * DIM + k0 + gofs[it],
                    &bT[t * 8 + it * 2048]);
    }
    __syncthreads();
    bf16x8 af[4], bfr[4];
#pragma unroll
    for (int mr = 0; mr < 4; ++mr)
      af[mr] = *(const bf16x8*)&aT[((wrow >> 1) + mr * 8 + rhalf) * 64 + up * 8];
#pragma unroll
    for (int mc = 0; mc < 4; ++mc)
      bfr[mc] = *(const bf16x8*)&bT[((wcol >> 1) + mc * 8 + rhalf) * 64 + up * 8];
#pragma unroll
    for (int mr = 0; mr < 4; ++mr)
#pragma unroll
      for (int mc = 0; mc < 4; ++mc)
        acc[mr][mc] =
            __builtin_amdgcn_mfma_f32_16x16x32_bf16(af[mr], bfr[mc], acc[mr][mc], 0, 0, 0);
    __syncthreads();
  }

  // Epilogue. C/D layout: col = lane&15, row = (lane>>4)*4 + reg.
  float sqc[4];
#pragma unroll
  for (int mc = 0; mc < 4; ++mc) sqc[mc] = sq[bcol + wcol + mc * 16 + lc];

  float cs[4] = {0.f, 0.f, 0.f, 0.f};  // column partial sums (off-diag tiles)

#pragma unroll
  for (int mr = 0; mr < 4; ++mr) {
#pragma unroll
    for (int reg = 0; reg < 4; ++reg) {
      const int r = brow + wrow + mr * 16 + q4 * 4 + reg;
      const float sr = sq[r];
      const int pc = r ^ (N2 / 2);
      float rs = 0.f;
#pragma unroll
      for (int mc = 0; mc < 4; ++mc) {
        const int c = bcol + wcol + mc * 16 + lc;
        const float g = acc[mr][mc][reg];
        const float d2 = fmaxf(sr + sqc[mc] - 2.f * g, 0.f);
        const float s = T2 * __builtin_amdgcn_rcpf(d2 + T2);
        if (c != r) rs += s;  // diagonal excluded exactly (diag tiles only)
        cs[mc] += s;          // unused on diag tiles
        if (c == pc) { spart[r] = s; spart[pc] = s; }  // off-diag only, 1 lane
      }
#pragma unroll
      for (int off = 1; off < 16; off <<= 1) rs += __shfl_xor(rs, off, 64);
      if (lc == 0) atomicAdd(&rowsum[r], rs);
    }
  }

  if (!diag) {
#pragma unroll
    for (int mc = 0; mc < 4; ++mc) {
      float v = cs[mc];
      v += __shfl_xor(v, 16, 64);
      v += __shfl_xor(v, 32, 64);
      if (lane < 16) atomicAdd(&rowsum[bcol + wcol + mc * 16 + lane], v);
    }
  }
}

// ---- final scalar reduction ---------------------------------------------
__global__ __launch_bounds__(256) void final_kernel(const float* __restrict__ rowsum,
                                                    const float* __restrict__ spart,
                                                    float* __restrict__ out) {
  const int t = threadIdx.x;
  float a = 0.f;
  for (int r = t; r < N2; r += 256) a += logf(rowsum[r]) - logf(spart[r]);
#pragma unroll
  for (int off = 1; off < 64; off <<= 1) a += __shfl_xor(a, off, 64);
  __shared__ float red[4];
  if ((t & 63) == 0) red[t >> 6] = a;
  __syncthreads();
  if (t == 0) out[0] = (red[0] + red[1] + red[2] + red[3]) * (1.0f / (float)N2);
}

extern "C" void kernel_launch(void* const* d_in, const int* in_sizes, int n_in,
                              void* d_out, int out_size, void* d_ws, size_t ws_size,
                              hipStream_t stream) {
  const float* features = (const float*)d_in[0];
  float* out = (float*)d_out;

  char* ws = (char*)d_ws;
  __bf16* fbf = (__bf16*)ws;                                     // 8 MB
  float* sq = (float*)(ws + (size_t)N2 * DIM * sizeof(__bf16));  // 32 KB
  float* rowsum = sq + N2;                                       // 32 KB
  float* spart = rowsum + N2;                                    // 32 KB

  prep_kernel<<<N2 / 2, 256, 0, stream>>>(features, fbf, sq, rowsum);
  gemm_kernel<<<NTILES, 256, 0, stream>>>(fbf, sq, rowsum, spart);
  final_kernel<<<1, 256, 0, stream>>>(rowsum, spart, out);
}